// Round 15
// baseline (271.056 us; speedup 1.0000x reference)
//
#include <hip/hip_runtime.h>

#define D 128
#define BSHIFT 7          // 128 nodes per bucket
#define EPB 8192          // edges per s1/s2 block (1024 threads x 8)

typedef unsigned int u32;
typedef unsigned short u16;
typedef unsigned char u8;
typedef __attribute__((ext_vector_type(8))) short bf16x8;
typedef __attribute__((ext_vector_type(2))) float f32x2;
typedef __attribute__((ext_vector_type(4))) float f32x4;
typedef __attribute__((ext_vector_type(4))) u32 u32x4;

#if __has_builtin(__builtin_amdgcn_cvt_pk_f32_fp8) && __has_builtin(__builtin_amdgcn_cvt_pk_fp8_f32)
#define HWFP8 1
#else
#define HWFP8 0
#endif

static __device__ __forceinline__ u16 f2bf(float x) {
    u32 u = __float_as_uint(x);
    u32 r = (u + 0x7fffu + ((u >> 16) & 1u)) >> 16;   // RNE
    return (u16)r;
}
static __device__ __forceinline__ u32 pack_bf(float lo, float hi) {
    return (u32)f2bf(lo) | ((u32)f2bf(hi) << 16);
}

// ---- fp8 codebook: HW OCP e4m3 (cvt builtins) with manual fallback ----

static __device__ __forceinline__ u32 enc8_sw(float x) {
    u32 u = __float_as_uint(x);
    u32 a = u & 0x7fffffffu;
    u32 r = a + 0x7FFFFu + ((a >> 20) & 1u);
    if (r >= 0x43E80000u) r = 0x43E00000u;            // clamp to 448
    u32 e = r >> 23;
    u32 b = (e < 121u) ? 0u : (((e - 120u) << 3) | ((r >> 20) & 7u));
    return b | ((u >> 31) << 7);
}
static __device__ __forceinline__ float dec8_sw(u32 t) {
    u32 m7 = t & 0x7fu;
    float f = __uint_as_float(((t & 0x80u) << 24) | ((m7 + 960u) << 20));
    return (m7 < 8u) ? 0.0f : f;
}

static __device__ __forceinline__ u32 enc8x4(float a, float b, float c, float d) {
#if HWFP8
    u32 w = __builtin_amdgcn_cvt_pk_fp8_f32(a, b, 0u, false);
    return __builtin_amdgcn_cvt_pk_fp8_f32(c, d, w, true);
#else
    return enc8_sw(a) | (enc8_sw(b) << 8) | (enc8_sw(c) << 16) | (enc8_sw(d) << 24);
#endif
}
static __device__ __forceinline__ u8 enc8x1(float v) {
#if HWFP8
    return (u8)(__builtin_amdgcn_cvt_pk_fp8_f32(v, v, 0u, false) & 0xFFu);
#else
    return (u8)enc8_sw(v);
#endif
}
static __device__ __forceinline__ f32x2 dec8x2(u32 t) {
#if HWFP8
    return __builtin_amdgcn_cvt_pk_f32_fp8(t, false);
#else
    f32x2 r;
    r.x = dec8_sw(t & 0xFFu);
    r.y = dec8_sw((t >> 8) & 0xFFu);
    return r;
#endif
}

// ---------------- zero_gcnt ----------------

__global__ __launch_bounds__(1024) void zero_gcnt(int* __restrict__ gcnt, int NBUCK) {
    for (int i = threadIdx.x; i < NBUCK; i += 1024) gcnt[i] = 0;
}

// ---------------- prep1: s1 bucket histogram | x->bf16+fp8 | weight concat ----------------

__global__ __launch_bounds__(1024) void prep1(
        const int* __restrict__ ei, int E, int NBUCK, int SB,
        int* __restrict__ gcnt, int* __restrict__ blockbase,
        const float* __restrict__ x, u32* __restrict__ xb, u32* __restrict__ x8,
        int n8, int XB,
        const float* __restrict__ Wl0, const float* __restrict__ Wr0,
        const float* __restrict__ Wl1, const float* __restrict__ Wr1,
        const float* __restrict__ Wl2, const float* __restrict__ Wr2,
        u16* __restrict__ Wcat) {
    int blk = blockIdx.x;
    int tid = threadIdx.x;
    if (blk < SB) {
        __shared__ int lh[1024];
        for (int b = tid; b < NBUCK; b += 1024) lh[b] = 0;
        __syncthreads();
        int base = blk * EPB;
        #pragma unroll
        for (int i = 0; i < EPB / 1024; ++i) {
            int e = base + i * 1024 + tid;
            if (e < E) atomicAdd(&lh[ei[E + e] >> BSHIFT], 1);
        }
        __syncthreads();
        for (int b = tid; b < NBUCK; b += 1024) {
            int c = lh[b];
            int g = atomicAdd(&gcnt[b], c);
            blockbase[(size_t)blk * NBUCK + b] = g;
        }
    } else if (blk < SB + XB) {
        int i = (blk - SB) * 1024 + tid;
        if (i < n8) {
            const f32x4* p = (const f32x4*)x + (size_t)i * 2;
            f32x4 a = __builtin_nontemporal_load(p);
            f32x4 q = __builtin_nontemporal_load(p + 1);
            u32x4 o;
            o.x = pack_bf(a.x, a.y);
            o.y = pack_bf(a.z, a.w);
            o.z = pack_bf(q.x, q.y);
            o.w = pack_bf(q.z, q.w);
            ((u32x4*)xb)[i] = o;
            x8[2 * i] = enc8x4(a.x, a.y, a.z, a.w);
            x8[2 * i + 1] = enc8x4(q.x, q.y, q.z, q.w);
        }
    } else {
        int idx = (blk - SB - XB) * 1024 + tid;   // 3*32768 total
        if (idx < 3 * 32768) {
            int l = idx >> 15;
            int r = idx & 32767;
            int j = r >> 8, k = r & 255;
            const float* Wl = (l == 0) ? Wl0 : (l == 1) ? Wl1 : Wl2;
            const float* Wr = (l == 0) ? Wr0 : (l == 1) ? Wr1 : Wr2;
            float v = (k < 128) ? Wl[j * 128 + k] : Wr[j * 128 + (k - 128)];
            Wcat[idx] = f2bf(v);
        }
    }
}

// ---------------- s2: LDS bucket-sort then coalesced write of packed pairs ----------------
// pair = (dst & 127) << 17 | src   (needs N <= 131072)

__global__ __launch_bounds__(1024) void s2_scatter(const int* __restrict__ ei, int E, int NBUCK,
                                                   const int* __restrict__ gcnt,
                                                   const int* __restrict__ blockbase,
                                                   u32* __restrict__ pairs,
                                                   int* __restrict__ bstart) {
    __shared__ u32 spair[EPB];       // 32 KB sorted pairs
    __shared__ u16 sbuck[EPB];       // 16 KB bucket id per slot
    __shared__ int lh[1024];
    __shared__ int lstart[1024];
    __shared__ int bb[1024];
    __shared__ int wsum[16];
    __shared__ int total_s;
    int tid = threadIdx.x, lane = tid & 63, wid = tid >> 6;

    {
        int v = (tid < NBUCK) ? gcnt[tid] : 0;
        int x = v;
        #pragma unroll
        for (int off = 1; off < 64; off <<= 1) {
            int t = __shfl_up(x, off);
            if (lane >= off) x += t;
        }
        if (lane == 63) wsum[wid] = x;
        __syncthreads();
        if (tid == 0) {
            int acc = 0;
            #pragma unroll
            for (int w = 0; w < 16; ++w) { int t = wsum[w]; wsum[w] = acc; acc += t; }
            total_s = acc;
        }
        __syncthreads();
        int excl = wsum[wid] + (x - v);
        if (tid < NBUCK) {
            bb[tid] = excl + blockbase[(size_t)blockIdx.x * NBUCK + tid];
            if (blockIdx.x == 0) bstart[tid] = excl;
        }
        if (blockIdx.x == 0 && tid == 0) bstart[NBUCK] = total_s;
        lh[tid] = 0;
    }
    __syncthreads();

    int base = blockIdx.x * EPB;
    int nedge = E - base; if (nedge > EPB) nedge = EPB;
    int dv[EPB / 1024], sv[EPB / 1024];
    #pragma unroll
    for (int i = 0; i < EPB / 1024; ++i) {
        int e = base + i * 1024 + tid;
        if (e < E) {
            dv[i] = ei[E + e];
            sv[i] = ei[e];
            atomicAdd(&lh[dv[i] >> BSHIFT], 1);
        } else dv[i] = -1;
    }
    __syncthreads();

    {
        int v = lh[tid];
        int x = v;
        #pragma unroll
        for (int off = 1; off < 64; off <<= 1) {
            int t = __shfl_up(x, off);
            if (lane >= off) x += t;
        }
        if (lane == 63) wsum[wid] = x;
        __syncthreads();
        if (tid == 0) {
            int acc = 0;
            #pragma unroll
            for (int w = 0; w < 16; ++w) { int t = wsum[w]; wsum[w] = acc; acc += t; }
        }
        __syncthreads();
        lstart[tid] = wsum[wid] + (x - v);
        __syncthreads();
        lh[tid] = 0;
    }
    __syncthreads();

    #pragma unroll
    for (int i = 0; i < EPB / 1024; ++i) {
        if (dv[i] >= 0) {
            int b = dv[i] >> BSHIFT;
            int pos = lstart[b] + atomicAdd(&lh[b], 1);
            spair[pos] = ((u32)(dv[i] & ((1 << BSHIFT) - 1)) << 17) | (u32)sv[i];
            sbuck[pos] = (u16)b;
        }
    }
    __syncthreads();

    #pragma unroll
    for (int i = 0; i < EPB / 1024; ++i) {
        int slot = i * 1024 + tid;
        if (slot < nedge) {
            int b = sbuck[slot];
            __builtin_nontemporal_store(spair[slot], &pairs[bb[b] + (slot - lstart[b])]);
        }
    }
}

// ---------------- s3: per-bucket CSR finalize ----------------

__global__ __launch_bounds__(256) void s3_csr(const u32* __restrict__ pairs,
                                              const int* __restrict__ bstart,
                                              int* __restrict__ row_start,
                                              int* __restrict__ col, int N, int NBUCK) {
    __shared__ int lcnt[128];
    __shared__ int lstart[128];
    int b = blockIdx.x;
    int tid = threadIdx.x;
    int bs = bstart[b], be = bstart[b + 1];
    int cnt = be - bs;
    int node_base = b << BSHIFT;
    if (tid < 128) lcnt[tid] = 0;
    __syncthreads();
    for (int i = tid; i < cnt; i += 256)
        atomicAdd(&lcnt[pairs[bs + i] >> 17], 1);
    __syncthreads();
    if (tid == 0) {
        int acc = 0;
        for (int t = 0; t < 128; ++t) { lstart[t] = acc; acc += lcnt[t]; }
    }
    __syncthreads();
    if (tid < 128) {
        int node = node_base + tid;
        if (node < N) row_start[node] = bs + lstart[tid];
        lcnt[tid] = 0;                   // reuse as cursor
    }
    if (b == NBUCK - 1 && tid == 0) row_start[N] = be;
    __syncthreads();
    for (int i = tid; i < cnt; i += 256) {
        u32 pr = pairs[bs + i];
        int ld = pr >> 17;
        int l = atomicAdd(&lcnt[ld], 1);
        col[bs + lstart[ld] + l] = (int)(pr & 0x1FFFFu);
    }
}

// ---------------- mean aggregation: 2 nodes/wave, 32-lane fp8 rows ----------------
// lanes 0-31 gather node n0, lanes 32-63 node n1 -> 2x outstanding rows/wave.
// Ladder driven by md = max(deg0,deg1), wave-uniform (scalar row_start reads);
// shorter half clamps col to its last valid neighbor (line already resident) and
// zero-masks the contribution -> arithmetic identical to 1-node version.

template <int B>
static __device__ __forceinline__ void gather2(const u32* __restrict__ h32,
                                               const int* __restrict__ col,
                                               int p, int s0h, int degh, int l32,
                                               float& a0, float& a1, float& a2, float& a3) {
    int c[B];
    #pragma unroll
    for (int q = 0; q < B; ++q) {
        int idx = p + q;
        if (idx > degh - 1) idx = degh - 1;
        if (idx < 0) idx = 0;
        c[q] = col[s0h + idx];
    }
    u32 u[B];
    #pragma unroll
    for (int q = 0; q < B; ++q) u[q] = h32[(size_t)c[q] * 32 + l32];
    #pragma unroll
    for (int q = 0; q < B; ++q) {
        u32 m = (p + q < degh) ? u[q] : 0u;
        f32x2 lo = dec8x2(m & 0xFFFFu);
        f32x2 hi = dec8x2(m >> 16);
        a0 += lo.x; a1 += lo.y; a2 += hi.x; a3 += hi.y;
    }
}

__global__ __launch_bounds__(256) void agg_fp8(const u32* __restrict__ h32,  // [N][32] u32 fp8
                                               const int* __restrict__ row_start,
                                               const int* __restrict__ col,
                                               u32* __restrict__ agg32, int N) {
    int lane = threadIdx.x & 63;
    int wid = threadIdx.x >> 6;
    int half = lane >> 5;
    int l32 = lane & 31;
    int n0 = __builtin_amdgcn_readfirstlane(blockIdx.x * 8 + wid * 2);
    if (n0 >= N) return;
    bool v1 = (n0 + 1 < N);

    int s00 = __builtin_amdgcn_readfirstlane(row_start[n0]);
    int s01 = __builtin_amdgcn_readfirstlane(row_start[n0 + 1]);
    int s02 = v1 ? __builtin_amdgcn_readfirstlane(row_start[n0 + 2]) : s01;
    int deg0 = s01 - s00;
    int deg1 = s02 - s01;
    int md = deg0 > deg1 ? deg0 : deg1;

    int s0h = half ? s01 : s00;
    int degh = half ? deg1 : deg0;

    float a0 = 0.f, a1 = 0.f, a2 = 0.f, a3 = 0.f;
    int p = 0;
    while (p + 16 <= md) { gather2<16>(h32, col, p, s0h, degh, l32, a0, a1, a2, a3); p += 16; }
    if (p + 8 <= md)     { gather2<8>(h32, col, p, s0h, degh, l32, a0, a1, a2, a3);  p += 8; }
    if (p + 4 <= md)     { gather2<4>(h32, col, p, s0h, degh, l32, a0, a1, a2, a3);  p += 4; }
    if (p + 2 <= md)     { gather2<2>(h32, col, p, s0h, degh, l32, a0, a1, a2, a3);  p += 2; }
    if (p < md)          { gather2<1>(h32, col, p, s0h, degh, l32, a0, a1, a2, a3); }

    if (half == 0 || v1) {
        float inv = 1.0f / fmaxf((float)degh, 1.0f);
        uint2 o;
        o.x = pack_bf(a0 * inv, a1 * inv);
        o.y = pack_bf(a2 * inv, a3 * inv);
        *(uint2*)(agg32 + (size_t)(n0 + half) * 64 + l32 * 2) = o;
    }
}

// ---------------- fused dual GEMM via MFMA ----------------

template <bool RELU, bool OUT_F32>
__global__ __launch_bounds__(256) void gemm_mfma(const u16* __restrict__ aggb,  // [N][128]
                                                 const u16* __restrict__ hb,    // [N][128]
                                                 const u16* __restrict__ Wcat,  // [128][256]
                                                 const float* __restrict__ bias,
                                                 u16* __restrict__ out_bf,
                                                 u8* __restrict__ out_fp8,
                                                 float* __restrict__ out_f32, int N) {
    __shared__ u16 s_a[64 * 256];   // 32 KB, XOR-swizzled rows
    int tid = threadIdx.x;
    int base = blockIdx.x * 64;
    int nrows = N - base; if (nrows > 64) nrows = 64;

    #pragma unroll
    for (int i = 0; i < 8; ++i) {
        int c = tid + i * 256;
        int row = c >> 5;
        int c16 = c & 31;
        int kbyte = (c16 * 16) ^ ((row & 7) << 4);
        uint4 v = make_uint4(0u, 0u, 0u, 0u);
        if (row < nrows) {
            const u16* src = (c16 < 16) ? (aggb + (size_t)(base + row) * 128 + c16 * 8)
                                        : (hb + (size_t)(base + row) * 128 + (c16 - 16) * 8);
            v = *(const uint4*)src;
        }
        *(uint4*)((char*)s_a + row * 512 + kbyte) = v;
    }
    __syncthreads();

    int lane = tid & 63;
    int wid = tid >> 6;
    int colbase = wid * 32;
    int jb = lane & 15;
    int kq = (lane >> 4) * 8;

    bf16x8 bfr[8][2];
    #pragma unroll
    for (int ks = 0; ks < 8; ++ks)
        #pragma unroll
        for (int n = 0; n < 2; ++n) {
            int j = colbase + n * 16 + jb;
            bfr[ks][n] = *(const bf16x8*)(Wcat + (size_t)j * 256 + ks * 32 + kq);
        }

    f32x4 acc[4][2];
    #pragma unroll
    for (int m = 0; m < 4; ++m)
        #pragma unroll
        for (int n = 0; n < 2; ++n)
            acc[m][n] = (f32x4){0.f, 0.f, 0.f, 0.f};

    #pragma unroll
    for (int ks = 0; ks < 8; ++ks) {
        bf16x8 afr[4];
        #pragma unroll
        for (int m = 0; m < 4; ++m) {
            int row = m * 16 + jb;
            int kbyte = (ks * 64 + kq * 2) ^ ((row & 7) << 4);
            afr[m] = *(const bf16x8*)((const char*)s_a + row * 512 + kbyte);
        }
        #pragma unroll
        for (int m = 0; m < 4; ++m)
            #pragma unroll
            for (int n = 0; n < 2; ++n)
                acc[m][n] = __builtin_amdgcn_mfma_f32_16x16x32_bf16(afr[m], bfr[ks][n],
                                                                    acc[m][n], 0, 0, 0);
    }

    float bv[2];
    #pragma unroll
    for (int n = 0; n < 2; ++n) bv[n] = bias[colbase + n * 16 + jb];

    #pragma unroll
    for (int m = 0; m < 4; ++m)
        #pragma unroll
        for (int n = 0; n < 2; ++n) {
            int colj = colbase + n * 16 + jb;
            #pragma unroll
            for (int r = 0; r < 4; ++r) {
                int row = m * 16 + (lane >> 4) * 4 + r;
                if (row < nrows) {
                    float v = acc[m][n][r] + bv[n];
                    if (RELU) v = fmaxf(v, 0.f);
                    size_t o = (size_t)(base + row) * 128 + colj;
                    if (OUT_F32) {
                        __builtin_nontemporal_store(v, &out_f32[o]);
                    } else {
                        out_bf[o] = f2bf(v);
                        out_fp8[o] = enc8x1(v);
                    }
                }
            }
        }
}

// ---------------- launch ----------------

extern "C" void kernel_launch(void* const* d_in, const int* in_sizes, int n_in,
                              void* d_out, int out_size, void* d_ws, size_t ws_size,
                              hipStream_t stream) {
    const float* x   = (const float*)d_in[0];
    const int*   ei  = (const int*)d_in[1];
    const float* Wl0 = (const float*)d_in[2];
    const float* bl0 = (const float*)d_in[3];
    const float* Wr0 = (const float*)d_in[4];
    const float* Wl1 = (const float*)d_in[5];
    const float* bl1 = (const float*)d_in[6];
    const float* Wr1 = (const float*)d_in[7];
    const float* Wl2 = (const float*)d_in[8];
    const float* bl2 = (const float*)d_in[9];
    const float* Wr2 = (const float*)d_in[10];

    const int N = in_sizes[0] / D;
    const int E = in_sizes[1] / 2;
    const int NBUCK = (N + 127) >> BSHIFT;          // <=1024 for N<=131072
    const int SB = (E + EPB - 1) / EPB;

    char* ws = (char*)d_ws;
    size_t off = 0;
    auto alloc = [&](size_t bytes) {
        void* p = ws + off;
        off = (off + bytes + 255) & ~(size_t)255;
        return p;
    };
    u16* xb        = (u16*)alloc((size_t)N * D * 2);   // layer-0 input; reused as h2b
    u16* h1b       = (u16*)alloc((size_t)N * D * 2);
    u16* aggb      = (u16*)alloc((size_t)N * D * 2);   // also aliases `pairs` pre-agg
    u8*  x8        = (u8*)alloc((size_t)N * D);        // fp8 gather copies
    u8*  h1_8      = (u8*)alloc((size_t)N * D);
    u16* Wcat      = (u16*)alloc(3 * (size_t)D * 256 * 2);
    int* gcnt      = (int*)alloc((size_t)NBUCK * 4);
    int* bstart    = (int*)alloc((size_t)(NBUCK + 1) * 4);
    int* blockbase = (int*)alloc((size_t)SB * NBUCK * 4);
    int* row_start = (int*)alloc((size_t)(N + 1) * 4);
    int* colv      = (int*)alloc((size_t)E * 4);
    (void)ws_size; (void)n_in; (void)out_size;
    u16* h2b = xb;                 // alias: xb dead after layer-1 GEMM
    u8*  h2_8 = x8;                // alias: x8 dead after layer-0 agg
    u32* pairs = (u32*)aggb;       // alias: pairs dead before first agg write

    const int n8 = N * D / 8;
    const int XB = (n8 + 1023) / 1024;
    const int WB = (3 * 32768 + 1023) / 1024;
    zero_gcnt<<<1, 1024, 0, stream>>>(gcnt, NBUCK);
    prep1<<<SB + XB + WB, 1024, 0, stream>>>(ei, E, NBUCK, SB, gcnt, blockbase,
                                             x, (u32*)xb, (u32*)x8, n8, XB,
                                             Wl0, Wr0, Wl1, Wr1, Wl2, Wr2, Wcat);
    s2_scatter<<<SB, 1024, 0, stream>>>(ei, E, NBUCK, gcnt, blockbase, pairs, bstart);
    s3_csr<<<NBUCK, 256, 0, stream>>>(pairs, bstart, row_start, colv, N, NBUCK);

    float* out = (float*)d_out;
    int agrid = (N + 7) / 8;
    int ggrid = (N + 63) / 64;

    // layer 0: x -> h1 (relu)
    agg_fp8<<<agrid, 256, 0, stream>>>((const u32*)x8, row_start, colv, (u32*)aggb, N);
    gemm_mfma<true, false><<<ggrid, 256, 0, stream>>>(aggb, xb, Wcat + 0 * D * 256, bl0,
                                                      h1b, h1_8, nullptr, N);
    // layer 1: h1 -> h2 (relu)
    agg_fp8<<<agrid, 256, 0, stream>>>((const u32*)h1_8, row_start, colv, (u32*)aggb, N);
    gemm_mfma<true, false><<<ggrid, 256, 0, stream>>>(aggb, h1b, Wcat + 1 * D * 256, bl1,
                                                      h2b, h2_8, nullptr, N);
    // layer 2: h2 -> d_out (f32, no relu)
    agg_fp8<<<agrid, 256, 0, stream>>>((const u32*)h2_8, row_start, colv, (u32*)aggb, N);
    gemm_mfma<false, true><<<ggrid, 256, 0, stream>>>(aggb, h2b, Wcat + 2 * D * 256, bl2,
                                                      nullptr, nullptr, out, N);
}

// Round 16
// 263.994 us; speedup vs baseline: 1.0268x; 1.0268x over previous
//
#include <hip/hip_runtime.h>

#define D 128
#define BSHIFT 7          // 128 nodes per bucket
#define EPB 8192          // edges per s1/s2 block (1024 threads x 8)

typedef unsigned int u32;
typedef unsigned short u16;
typedef unsigned char u8;
typedef __attribute__((ext_vector_type(8))) short bf16x8;
typedef __attribute__((ext_vector_type(2))) float f32x2;
typedef __attribute__((ext_vector_type(4))) float f32x4;
typedef __attribute__((ext_vector_type(4))) u32 u32x4;

#if __has_builtin(__builtin_amdgcn_cvt_pk_f32_fp8) && __has_builtin(__builtin_amdgcn_cvt_pk_fp8_f32)
#define HWFP8 1
#else
#define HWFP8 0
#endif

static __device__ __forceinline__ u16 f2bf(float x) {
    u32 u = __float_as_uint(x);
    u32 r = (u + 0x7fffu + ((u >> 16) & 1u)) >> 16;   // RNE
    return (u16)r;
}
static __device__ __forceinline__ u32 pack_bf(float lo, float hi) {
    return (u32)f2bf(lo) | ((u32)f2bf(hi) << 16);
}

// ---- fp8 codebook: HW OCP e4m3 (cvt builtins) with manual fallback ----

static __device__ __forceinline__ u32 enc8_sw(float x) {
    u32 u = __float_as_uint(x);
    u32 a = u & 0x7fffffffu;
    u32 r = a + 0x7FFFFu + ((a >> 20) & 1u);
    if (r >= 0x43E80000u) r = 0x43E00000u;            // clamp to 448
    u32 e = r >> 23;
    u32 b = (e < 121u) ? 0u : (((e - 120u) << 3) | ((r >> 20) & 7u));
    return b | ((u >> 31) << 7);
}
static __device__ __forceinline__ float dec8_sw(u32 t) {
    u32 m7 = t & 0x7fu;
    float f = __uint_as_float(((t & 0x80u) << 24) | ((m7 + 960u) << 20));
    return (m7 < 8u) ? 0.0f : f;
}

static __device__ __forceinline__ u32 enc8x4(float a, float b, float c, float d) {
#if HWFP8
    u32 w = __builtin_amdgcn_cvt_pk_fp8_f32(a, b, 0u, false);
    return __builtin_amdgcn_cvt_pk_fp8_f32(c, d, w, true);
#else
    return enc8_sw(a) | (enc8_sw(b) << 8) | (enc8_sw(c) << 16) | (enc8_sw(d) << 24);
#endif
}
static __device__ __forceinline__ u8 enc8x1(float v) {
#if HWFP8
    return (u8)(__builtin_amdgcn_cvt_pk_fp8_f32(v, v, 0u, false) & 0xFFu);
#else
    return (u8)enc8_sw(v);
#endif
}
static __device__ __forceinline__ f32x2 dec8x2(u32 t) {
#if HWFP8
    return __builtin_amdgcn_cvt_pk_f32_fp8(t, false);
#else
    f32x2 r;
    r.x = dec8_sw(t & 0xFFu);
    r.y = dec8_sw((t >> 8) & 0xFFu);
    return r;
#endif
}

// ---------------- zero_gcnt ----------------

__global__ __launch_bounds__(1024) void zero_gcnt(int* __restrict__ gcnt, int NBUCK) {
    for (int i = threadIdx.x; i < NBUCK; i += 1024) gcnt[i] = 0;
}

// ---------------- prep1: s1 bucket histogram | x->bf16+fp8 | weight concat ----------------

__global__ __launch_bounds__(1024) void prep1(
        const int* __restrict__ ei, int E, int NBUCK, int SB,
        int* __restrict__ gcnt, int* __restrict__ blockbase,
        const float* __restrict__ x, u32* __restrict__ xb, u32* __restrict__ x8,
        int n8, int XB,
        const float* __restrict__ Wl0, const float* __restrict__ Wr0,
        const float* __restrict__ Wl1, const float* __restrict__ Wr1,
        const float* __restrict__ Wl2, const float* __restrict__ Wr2,
        u16* __restrict__ Wcat) {
    int blk = blockIdx.x;
    int tid = threadIdx.x;
    if (blk < SB) {
        __shared__ int lh[1024];
        for (int b = tid; b < NBUCK; b += 1024) lh[b] = 0;
        __syncthreads();
        int base = blk * EPB;
        #pragma unroll
        for (int i = 0; i < EPB / 1024; ++i) {
            int e = base + i * 1024 + tid;
            if (e < E) atomicAdd(&lh[ei[E + e] >> BSHIFT], 1);
        }
        __syncthreads();
        for (int b = tid; b < NBUCK; b += 1024) {
            int c = lh[b];
            int g = atomicAdd(&gcnt[b], c);
            blockbase[(size_t)blk * NBUCK + b] = g;
        }
    } else if (blk < SB + XB) {
        int i = (blk - SB) * 1024 + tid;
        if (i < n8) {
            const f32x4* p = (const f32x4*)x + (size_t)i * 2;
            f32x4 a = __builtin_nontemporal_load(p);
            f32x4 q = __builtin_nontemporal_load(p + 1);
            u32x4 o;
            o.x = pack_bf(a.x, a.y);
            o.y = pack_bf(a.z, a.w);
            o.z = pack_bf(q.x, q.y);
            o.w = pack_bf(q.z, q.w);
            ((u32x4*)xb)[i] = o;
            x8[2 * i] = enc8x4(a.x, a.y, a.z, a.w);
            x8[2 * i + 1] = enc8x4(q.x, q.y, q.z, q.w);
        }
    } else {
        int idx = (blk - SB - XB) * 1024 + tid;   // 3*32768 total
        if (idx < 3 * 32768) {
            int l = idx >> 15;
            int r = idx & 32767;
            int j = r >> 8, k = r & 255;
            const float* Wl = (l == 0) ? Wl0 : (l == 1) ? Wl1 : Wl2;
            const float* Wr = (l == 0) ? Wr0 : (l == 1) ? Wr1 : Wr2;
            float v = (k < 128) ? Wl[j * 128 + k] : Wr[j * 128 + (k - 128)];
            Wcat[idx] = f2bf(v);
        }
    }
}

// ---------------- s2: LDS bucket-sort then coalesced write of packed pairs ----------------
// pair = (dst & 127) << 17 | src   (needs N <= 131072)

__global__ __launch_bounds__(1024) void s2_scatter(const int* __restrict__ ei, int E, int NBUCK,
                                                   const int* __restrict__ gcnt,
                                                   const int* __restrict__ blockbase,
                                                   u32* __restrict__ pairs,
                                                   int* __restrict__ bstart) {
    __shared__ u32 spair[EPB];       // 32 KB sorted pairs
    __shared__ u16 sbuck[EPB];       // 16 KB bucket id per slot
    __shared__ int lh[1024];
    __shared__ int lstart[1024];
    __shared__ int bb[1024];
    __shared__ int wsum[16];
    __shared__ int total_s;
    int tid = threadIdx.x, lane = tid & 63, wid = tid >> 6;

    {
        int v = (tid < NBUCK) ? gcnt[tid] : 0;
        int x = v;
        #pragma unroll
        for (int off = 1; off < 64; off <<= 1) {
            int t = __shfl_up(x, off);
            if (lane >= off) x += t;
        }
        if (lane == 63) wsum[wid] = x;
        __syncthreads();
        if (tid == 0) {
            int acc = 0;
            #pragma unroll
            for (int w = 0; w < 16; ++w) { int t = wsum[w]; wsum[w] = acc; acc += t; }
            total_s = acc;
        }
        __syncthreads();
        int excl = wsum[wid] + (x - v);
        if (tid < NBUCK) {
            bb[tid] = excl + blockbase[(size_t)blockIdx.x * NBUCK + tid];
            if (blockIdx.x == 0) bstart[tid] = excl;
        }
        if (blockIdx.x == 0 && tid == 0) bstart[NBUCK] = total_s;
        lh[tid] = 0;
    }
    __syncthreads();

    int base = blockIdx.x * EPB;
    int nedge = E - base; if (nedge > EPB) nedge = EPB;
    int dv[EPB / 1024], sv[EPB / 1024];
    #pragma unroll
    for (int i = 0; i < EPB / 1024; ++i) {
        int e = base + i * 1024 + tid;
        if (e < E) {
            dv[i] = ei[E + e];
            sv[i] = ei[e];
            atomicAdd(&lh[dv[i] >> BSHIFT], 1);
        } else dv[i] = -1;
    }
    __syncthreads();

    {
        int v = lh[tid];
        int x = v;
        #pragma unroll
        for (int off = 1; off < 64; off <<= 1) {
            int t = __shfl_up(x, off);
            if (lane >= off) x += t;
        }
        if (lane == 63) wsum[wid] = x;
        __syncthreads();
        if (tid == 0) {
            int acc = 0;
            #pragma unroll
            for (int w = 0; w < 16; ++w) { int t = wsum[w]; wsum[w] = acc; acc += t; }
        }
        __syncthreads();
        lstart[tid] = wsum[wid] + (x - v);
        __syncthreads();
        lh[tid] = 0;
    }
    __syncthreads();

    #pragma unroll
    for (int i = 0; i < EPB / 1024; ++i) {
        if (dv[i] >= 0) {
            int b = dv[i] >> BSHIFT;
            int pos = lstart[b] + atomicAdd(&lh[b], 1);
            spair[pos] = ((u32)(dv[i] & ((1 << BSHIFT) - 1)) << 17) | (u32)sv[i];
            sbuck[pos] = (u16)b;
        }
    }
    __syncthreads();

    #pragma unroll
    for (int i = 0; i < EPB / 1024; ++i) {
        int slot = i * 1024 + tid;
        if (slot < nedge) {
            int b = sbuck[slot];
            __builtin_nontemporal_store(spair[slot], &pairs[bb[b] + (slot - lstart[b])]);
        }
    }
}

// ---------------- s3: per-bucket CSR finalize ----------------

__global__ __launch_bounds__(256) void s3_csr(const u32* __restrict__ pairs,
                                              const int* __restrict__ bstart,
                                              int* __restrict__ row_start,
                                              int* __restrict__ col, int N, int NBUCK) {
    __shared__ int lcnt[128];
    __shared__ int lstart[128];
    int b = blockIdx.x;
    int tid = threadIdx.x;
    int bs = bstart[b], be = bstart[b + 1];
    int cnt = be - bs;
    int node_base = b << BSHIFT;
    if (tid < 128) lcnt[tid] = 0;
    __syncthreads();
    for (int i = tid; i < cnt; i += 256)
        atomicAdd(&lcnt[pairs[bs + i] >> 17], 1);
    __syncthreads();
    if (tid == 0) {
        int acc = 0;
        for (int t = 0; t < 128; ++t) { lstart[t] = acc; acc += lcnt[t]; }
    }
    __syncthreads();
    if (tid < 128) {
        int node = node_base + tid;
        if (node < N) row_start[node] = bs + lstart[tid];
        lcnt[tid] = 0;                   // reuse as cursor
    }
    if (b == NBUCK - 1 && tid == 0) row_start[N] = be;
    __syncthreads();
    for (int i = tid; i < cnt; i += 256) {
        u32 pr = pairs[bs + i];
        int ld = pr >> 17;
        int l = atomicAdd(&lcnt[ld], 1);
        col[bs + lstart[ld] + l] = (int)(pr & 0x1FFFFu);
    }
}

// ---------------- mean aggregation over fp8 rows (HW cvt decode, 1 node/wave) ----------------

template <int B>
static __device__ __forceinline__ void gather8(const u16* __restrict__ h8,
                                               const int* __restrict__ col,
                                               int p, int lane,
                                               float& ax, float& ay) {
    int c[B];
    #pragma unroll
    for (int q = 0; q < B; ++q) c[q] = col[p + q];
    u16 u[B];
    #pragma unroll
    for (int q = 0; q < B; ++q) u[q] = h8[(size_t)c[q] * 64 + lane];
    #pragma unroll
    for (int q = 0; q < B; ++q) {
        f32x2 v = dec8x2((u32)u[q]);
        ax += v.x;
        ay += v.y;
    }
}

__global__ __launch_bounds__(256) void agg_fp8(const u16* __restrict__ h8,   // [N][64] u16
                                               const int* __restrict__ row_start,
                                               const int* __restrict__ col,
                                               u32* __restrict__ agg32, int N) {
    int node = blockIdx.x * 4 + (threadIdx.x >> 6);
    node = __builtin_amdgcn_readfirstlane(node);
    if (node >= N) return;
    int lane = threadIdx.x & 63;
    int s0 = row_start[node], s1 = row_start[node + 1];
    float ax = 0.f, ay = 0.f;
    int p = s0;
    while (p + 16 <= s1) { gather8<16>(h8, col, p, lane, ax, ay); p += 16; }
    if (p + 8 <= s1)     { gather8<8>(h8, col, p, lane, ax, ay);  p += 8; }
    if (p + 4 <= s1)     { gather8<4>(h8, col, p, lane, ax, ay);  p += 4; }
    if (p + 2 <= s1)     { gather8<2>(h8, col, p, lane, ax, ay);  p += 2; }
    if (p < s1)          { gather8<1>(h8, col, p, lane, ax, ay); }
    float inv = 1.0f / fmaxf((float)(s1 - s0), 1.0f);
    agg32[(size_t)node * 64 + lane] = pack_bf(ax * inv, ay * inv);
}

// ---------------- fused dual GEMM via MFMA ----------------

template <bool RELU, bool OUT_F32>
__global__ __launch_bounds__(256) void gemm_mfma(const u16* __restrict__ aggb,  // [N][128]
                                                 const u16* __restrict__ hb,    // [N][128]
                                                 const u16* __restrict__ Wcat,  // [128][256]
                                                 const float* __restrict__ bias,
                                                 u16* __restrict__ out_bf,
                                                 u8* __restrict__ out_fp8,
                                                 float* __restrict__ out_f32, int N) {
    __shared__ u16 s_a[64 * 256];   // 32 KB, XOR-swizzled rows
    int tid = threadIdx.x;
    int base = blockIdx.x * 64;
    int nrows = N - base; if (nrows > 64) nrows = 64;

    #pragma unroll
    for (int i = 0; i < 8; ++i) {
        int c = tid + i * 256;
        int row = c >> 5;
        int c16 = c & 31;
        int kbyte = (c16 * 16) ^ ((row & 7) << 4);
        uint4 v = make_uint4(0u, 0u, 0u, 0u);
        if (row < nrows) {
            const u16* src = (c16 < 16) ? (aggb + (size_t)(base + row) * 128 + c16 * 8)
                                        : (hb + (size_t)(base + row) * 128 + (c16 - 16) * 8);
            v = *(const uint4*)src;
        }
        *(uint4*)((char*)s_a + row * 512 + kbyte) = v;
    }
    __syncthreads();

    int lane = tid & 63;
    int wid = tid >> 6;
    int colbase = wid * 32;
    int jb = lane & 15;
    int kq = (lane >> 4) * 8;

    bf16x8 bfr[8][2];
    #pragma unroll
    for (int ks = 0; ks < 8; ++ks)
        #pragma unroll
        for (int n = 0; n < 2; ++n) {
            int j = colbase + n * 16 + jb;
            bfr[ks][n] = *(const bf16x8*)(Wcat + (size_t)j * 256 + ks * 32 + kq);
        }

    f32x4 acc[4][2];
    #pragma unroll
    for (int m = 0; m < 4; ++m)
        #pragma unroll
        for (int n = 0; n < 2; ++n)
            acc[m][n] = (f32x4){0.f, 0.f, 0.f, 0.f};

    #pragma unroll
    for (int ks = 0; ks < 8; ++ks) {
        bf16x8 afr[4];
        #pragma unroll
        for (int m = 0; m < 4; ++m) {
            int row = m * 16 + jb;
            int kbyte = (ks * 64 + kq * 2) ^ ((row & 7) << 4);
            afr[m] = *(const bf16x8*)((const char*)s_a + row * 512 + kbyte);
        }
        #pragma unroll
        for (int m = 0; m < 4; ++m)
            #pragma unroll
            for (int n = 0; n < 2; ++n)
                acc[m][n] = __builtin_amdgcn_mfma_f32_16x16x32_bf16(afr[m], bfr[ks][n],
                                                                    acc[m][n], 0, 0, 0);
    }

    float bv[2];
    #pragma unroll
    for (int n = 0; n < 2; ++n) bv[n] = bias[colbase + n * 16 + jb];

    #pragma unroll
    for (int m = 0; m < 4; ++m)
        #pragma unroll
        for (int n = 0; n < 2; ++n) {
            int colj = colbase + n * 16 + jb;
            #pragma unroll
            for (int r = 0; r < 4; ++r) {
                int row = m * 16 + (lane >> 4) * 4 + r;
                if (row < nrows) {
                    float v = acc[m][n][r] + bv[n];
                    if (RELU) v = fmaxf(v, 0.f);
                    size_t o = (size_t)(base + row) * 128 + colj;
                    if (OUT_F32) {
                        __builtin_nontemporal_store(v, &out_f32[o]);
                    } else {
                        out_bf[o] = f2bf(v);
                        out_fp8[o] = enc8x1(v);
                    }
                }
            }
        }
}

// ---------------- launch ----------------

extern "C" void kernel_launch(void* const* d_in, const int* in_sizes, int n_in,
                              void* d_out, int out_size, void* d_ws, size_t ws_size,
                              hipStream_t stream) {
    const float* x   = (const float*)d_in[0];
    const int*   ei  = (const int*)d_in[1];
    const float* Wl0 = (const float*)d_in[2];
    const float* bl0 = (const float*)d_in[3];
    const float* Wr0 = (const float*)d_in[4];
    const float* Wl1 = (const float*)d_in[5];
    const float* bl1 = (const float*)d_in[6];
    const float* Wr1 = (const float*)d_in[7];
    const float* Wl2 = (const float*)d_in[8];
    const float* bl2 = (const float*)d_in[9];
    const float* Wr2 = (const float*)d_in[10];

    const int N = in_sizes[0] / D;
    const int E = in_sizes[1] / 2;
    const int NBUCK = (N + 127) >> BSHIFT;          // <=1024 for N<=131072
    const int SB = (E + EPB - 1) / EPB;

    char* ws = (char*)d_ws;
    size_t off = 0;
    auto alloc = [&](size_t bytes) {
        void* p = ws + off;
        off = (off + bytes + 255) & ~(size_t)255;
        return p;
    };
    u16* xb        = (u16*)alloc((size_t)N * D * 2);   // layer-0 input; reused as h2b
    u16* h1b       = (u16*)alloc((size_t)N * D * 2);
    u16* aggb      = (u16*)alloc((size_t)N * D * 2);   // also aliases `pairs` pre-agg
    u8*  x8        = (u8*)alloc((size_t)N * D);        // fp8 gather copies
    u8*  h1_8      = (u8*)alloc((size_t)N * D);
    u16* Wcat      = (u16*)alloc(3 * (size_t)D * 256 * 2);
    int* gcnt      = (int*)alloc((size_t)NBUCK * 4);
    int* bstart    = (int*)alloc((size_t)(NBUCK + 1) * 4);
    int* blockbase = (int*)alloc((size_t)SB * NBUCK * 4);
    int* row_start = (int*)alloc((size_t)(N + 1) * 4);
    int* colv      = (int*)alloc((size_t)E * 4);
    (void)ws_size; (void)n_in; (void)out_size;
    u16* h2b = xb;                 // alias: xb dead after layer-1 GEMM
    u8*  h2_8 = x8;                // alias: x8 dead after layer-0 agg
    u32* pairs = (u32*)aggb;       // alias: pairs dead before first agg write

    const int n8 = N * D / 8;
    const int XB = (n8 + 1023) / 1024;
    const int WB = (3 * 32768 + 1023) / 1024;
    zero_gcnt<<<1, 1024, 0, stream>>>(gcnt, NBUCK);
    prep1<<<SB + XB + WB, 1024, 0, stream>>>(ei, E, NBUCK, SB, gcnt, blockbase,
                                             x, (u32*)xb, (u32*)x8, n8, XB,
                                             Wl0, Wr0, Wl1, Wr1, Wl2, Wr2, Wcat);
    s2_scatter<<<SB, 1024, 0, stream>>>(ei, E, NBUCK, gcnt, blockbase, pairs, bstart);
    s3_csr<<<NBUCK, 256, 0, stream>>>(pairs, bstart, row_start, colv, N, NBUCK);

    float* out = (float*)d_out;
    int agrid = (N + 3) / 4;
    int ggrid = (N + 63) / 64;

    // layer 0: x -> h1 (relu)
    agg_fp8<<<agrid, 256, 0, stream>>>((const u16*)x8, row_start, colv, (u32*)aggb, N);
    gemm_mfma<true, false><<<ggrid, 256, 0, stream>>>(aggb, xb, Wcat + 0 * D * 256, bl0,
                                                      h1b, h1_8, nullptr, N);
    // layer 1: h1 -> h2 (relu)
    agg_fp8<<<agrid, 256, 0, stream>>>((const u16*)h1_8, row_start, colv, (u32*)aggb, N);
    gemm_mfma<true, false><<<ggrid, 256, 0, stream>>>(aggb, h1b, Wcat + 1 * D * 256, bl1,
                                                      h2b, h2_8, nullptr, N);
    // layer 2: h2 -> d_out (f32, no relu)
    agg_fp8<<<agrid, 256, 0, stream>>>((const u16*)h2_8, row_start, colv, (u32*)aggb, N);
    gemm_mfma<false, true><<<ggrid, 256, 0, stream>>>(aggb, h2b, Wcat + 2 * D * 256, bl2,
                                                      nullptr, nullptr, out, N);
}